// Round 10
// baseline (103.476 us; speedup 1.0000x reference)
//
#include <hip/hip_runtime.h>

#define N  192
#define N2 (N * N)
#define N3 (N * N * N)

// Block: 32x16 (x,y) tile marching ZC planes in z (axis0).
#define TX 32
#define TY 16
#define NT (TX * TY)          // 512 threads, 8 waves
#define ZC 12
#define GX (N / TX)           // 6
#define GY (N / TY)           // 12
#define GZ (N / ZC)           // 16
#define NBLK (GX * GY * GZ)   // 1152 (divisible by 8 XCDs)
#define UX (TX + 4)           // 36  (u/T halo +-2)
#define UY (TY + 4)           // 20
#define UP (UX * UY)          // 720
#define FX (TX + 2)           // 34  (flux halo +-1)
#define FY (TY + 2)           // 18
#define FP (FX * FY)          // 612

static constexpr float INV2DX     = (float)N / 2.0f;   // 96
static constexpr float SCALE2     = INV2DX * INV2DX;   // 9216 (exact)
static constexpr float MU_REF_F   = 1.8e-5f;
static constexpr float CP_OVER_PR = 1005.0f / 0.72f;
static constexpr float TWO_THIRDS = 2.0f / 3.0f;

__device__ __forceinline__ int wrapN(int a) {  // valid for a in [-N, 2N)
    if (a < 0)  a += N;
    if (a >= N) a -= N;
    return a;
}

struct Flux { float t00, t01, t02, t11, t12, t22, F0, F1, F2; };

// Flux at a site given its own column {zm, cc, zp} in registers; the 4
// xy-neighbors come from LDS (ds_read_b128 x4). No 1/(2dx) factor — the
// single INV2DX^2 is applied at the output store.
__device__ __forceinline__ Flux flux_eval_reg(const float4 zm, const float4 cc,
                                              const float4 zp,
                                              const float4* __restrict__ uC, int c)
{
    const float4 xp = uC[c + 1],  xm = uC[c - 1];
    const float4 yp = uC[c + UX], ym = uC[c - UX];

    const float d00 = zp.x - zm.x;
    const float d01 = yp.x - ym.x;
    const float d02 = xp.x - xm.x;
    const float d10 = zp.y - zm.y;
    const float d11 = yp.y - ym.y;
    const float d12 = xp.y - xm.y;
    const float d20 = zp.z - zm.z;
    const float d21 = yp.z - ym.z;
    const float d22 = xp.z - xm.z;
    const float dT0 = zp.w - zm.w;
    const float dT1 = yp.w - ym.w;
    const float dT2 = xp.w - xm.w;

    const float mu   = MU_REF_F * __powf(cc.w, 0.7f);
    const float mu2  = mu + mu;
    const float divu = d00 + d11 + d22;
    const float lam  = -TWO_THIRDS * mu * divu;

    Flux f;
    f.t00 = mu2 * d00 + lam;
    f.t11 = mu2 * d11 + lam;
    f.t22 = mu2 * d22 + lam;
    f.t01 = mu * (d01 + d10);
    f.t02 = mu * (d02 + d20);
    f.t12 = mu * (d12 + d21);
    const float kc = mu * CP_OVER_PR;
    f.F0 = kc * dT0 + f.t00 * cc.x + f.t01 * cc.y + f.t02 * cc.z;
    f.F1 = kc * dT1 + f.t01 * cc.x + f.t11 * cc.y + f.t12 * cc.z;
    f.F2 = kc * dT2 + f.t02 * cc.x + f.t12 * cc.y + f.t22 * cc.z;
    return f;
}

// Prologue-only variant: whole column from LDS.
__device__ __forceinline__ Flux flux_eval_lds(const float4* __restrict__ uM,
                                              const float4* __restrict__ uC,
                                              const float4* __restrict__ uP, int c)
{
    return flux_eval_reg(uM[c], uC[c], uP[c], uC, c);
}

// sf packing by derivative direction:
//   sfY[fi] = {t01, t11, t12, F1}  (read at fi +- FX for the y-derivative)
//   sfX[fi] = {t02, t12, t22, F2}  (read at fi +- 1  for the x-derivative)
__device__ __forceinline__ void sf_store(float4* __restrict__ sY, float4* __restrict__ sX,
                                         int fi, const Flux& f)
{
    sY[fi] = make_float4(f.t01, f.t11, f.t12, f.F1);
    sX[fi] = make_float4(f.t02, f.t12, f.t22, f.F2);
}

__global__ __launch_bounds__(NT)
void diffusion_zmarch_kernel(const float* __restrict__ u,
                             const float* __restrict__ Tp,
                             float* __restrict__ out)
{
    __shared__ float4 su4[3][UP];     // 3 rolling packed u/T planes (33.75 KB)
    __shared__ float4 sfY[FP];        // flux y-fields, SINGLE buffer (9.6 KB)
    __shared__ float4 sfX[FP];        // flux x-fields, SINGLE buffer (9.6 KB)
    // total 52.9 KB -> 3 blocks/CU x 8 waves = 24 waves/CU

    // ---- bijective XCD swizzle on the flat block id (NBLK % 8 == 0) ----
    const int id  = (int)blockIdx.x;
    const int nid = (id & 7) * (NBLK / 8) + (id >> 3);
    const int bzB = nid / (GX * GY);
    const int rem = nid % (GX * GY);
    const int bx  = (rem % GX) * TX;
    const int by  = (rem / GX) * TY;
    const int z0  = bzB * ZC;

    const int tx  = threadIdx.x & (TX - 1);
    const int ty  = threadIdx.x >> 5;
    const int tid = (int)threadIdx.x;

    const float* __restrict__ u0 = u;
    const float* __restrict__ u1 = u + N3;
    const float* __restrict__ u2 = u + 2 * N3;

    const int cu = (ty + 2) * UX + (tx + 2);   // interior u-site
    const int fi = (ty + 1) * FX + (tx + 1);   // interior flux-site

    // ---- work balancing across waves ----
    // halo flux sites -> waves 6.5-8 (tid 416..511); extra staging -> waves 0-5.
    const int ht = tid - (NT - 2 * (TX + TY));   // 96 halo sites, corners excl.
    int hfx = -1, hfy = -1;
    if (ht >= 0) {
        if (ht < TX)               { hfy = 0;      hfx = 1 + ht; }
        else if (ht < 2 * TX)      { hfy = FY - 1; hfx = 1 + ht - TX; }
        else if (ht < 2 * TX + TY) { hfx = 0;      hfy = 1 + ht - 2 * TX; }
        else                       { hfx = FX - 1; hfy = 1 + ht - 2 * TX - TY; }
    }
    const bool hasH = (ht >= 0);
    const int hcu = (hfy + 1) * UX + (hfx + 1);
    const int hfi = hfy * FX + hfx;

    // staging: site q0 = tid for all; the 208 extra sites spread over waves
    // 0-5, lanes 0-34 (q1 = NT + wv*35 + ln), so no wave carries two extras.
    const int  wv = tid >> 6, ln = tid & 63;
    const int  q0 = tid;
    const int  q1 = NT + wv * 35 + ln;
    const bool has2 = (ln < 35) && (wv < 6) && (q1 < UP);
    int ro0, ro1 = 0;
    {
        const int ux = q0 % UX, uy = q0 / UX;
        ro0 = wrapN(by + uy - 2) * N + wrapN(bx + ux - 2);
    }
    if (has2) {
        const int ux = q1 % UX, uy = q1 / UX;
        ro1 = wrapN(by + uy - 2) * N + wrapN(bx + ux - 2);
    }

#define STAGE_DIRECT(slot, zw)                                              \
    do {                                                                    \
        const int base_ = (zw) * N2;                                        \
        {  const int g_ = base_ + ro0;                                      \
           su4[slot][q0] = make_float4(u0[g_], u1[g_], u2[g_], Tp[g_]); }   \
        if (has2) {                                                         \
           const int g_ = base_ + ro1;                                      \
           su4[slot][q1] = make_float4(u0[g_], u1[g_], u2[g_], Tp[g_]); }   \
    } while (0)

    // ---- prologue ----
    STAGE_DIRECT(0, wrapN(z0 - 2));   // z0-2
    STAGE_DIRECT(1, wrapN(z0 - 1));   // z0-1
    STAGE_DIRECT(2, z0);              // z0
    __syncthreads();

    float t00m, t01m, t02m, F0m;      // flux(z-1) z-fields
    {
        const Flux fM = flux_eval_lds(su4[0], su4[1], su4[2], cu);
        t00m = fM.t00; t01m = fM.t01; t02m = fM.t02; F0m = fM.F0;
    }
    __syncthreads();                   // slot0 reads done
    STAGE_DIRECT(0, z0 + 1);          // slot0 <- z0+1
    __syncthreads();

    float t00c, t01c, t02c, F0c;      // flux(z) z-fields
    {
        const Flux fC = flux_eval_lds(su4[1], su4[2], su4[0], cu);
        t00c = fC.t00; t01c = fC.t01; t02c = fC.t02; F0c = fC.F0;
        sf_store(sfY, sfX, fi, fC);
        if (hasH) {
            const Flux h = flux_eval_lds(su4[1], su4[2], su4[0], hcu);
            sf_store(sfY, sfX, hfi, h);
        }
    }
    __syncthreads();                   // slot1 reads done, sf visible
    STAGE_DIRECT(1, z0 + 2);          // slot1 <- z0+2
    __syncthreads();

    // register z-pipeline: own-column values for the flux plane
    float4 rzm = su4[2][cu];          // u(z0)
    float4 rcc = su4[0][cu];          // u(z0+1)
    float4 hzm, hcc;
    if (hasH) { hzm = su4[2][hcu]; hcc = su4[0][hcu]; }

    // slots: pC = z+1 (xy-neighbor source), pP = z+2 (own-read), pW = overwrite
    float4 *pC = su4[0], *pP = su4[1], *pW = su4[2];

    int idx = z0 * N2 + (by + ty) * N + bx + tx;   // output index, += N2/iter
    int zw  = z0 + 3; if (zw >= N) zw -= N;        // prefetch plane, wrapped

    // ---- main loop: one output plane per iteration ----
    for (int it = 0; it < ZC; ++it) {
        // 1) issue next plane's global loads early (consumed at step 6)
        const bool pref = (it <= ZC - 2);
        float4 r0, r1;
        if (pref) {
            const int base_ = zw * N2;
            { const int g_ = base_ + ro0;
              r0 = make_float4(u0[g_], u1[g_], u2[g_], Tp[g_]); }
            if (has2) {
              const int g_ = base_ + ro1;
              r1 = make_float4(u0[g_], u1[g_], u2[g_], Tp[g_]); }
        }

        // 2) pre-barrier LDS reads: sf(z) xy-neighbors + own u-column at z+2
        const float4 yp = sfY[fi + FX], ym = sfY[fi - FX];
        const float4 xp = sfX[fi + 1],  xm = sfX[fi - 1];
        const float4 own = pP[cu];
        float4 hown;
        if (hasH) hown = pP[hcu];

        // 3) cheap mid-barrier: orders LDS reads vs the sf overwrites below,
        //    WITHOUT draining vmcnt — the prefetch globals stay in flight.
        asm volatile("s_waitcnt lgkmcnt(0)\n\ts_barrier" ::: "memory");

        // 4) flux(z+1): own column from regs; xy from pC (read-only this iter)
        const Flux fp_ = flux_eval_reg(rzm, rcc, own, pC, cu);
        Flux h;
        if (hasH) h = flux_eval_reg(hzm, hcc, hown, pC, hcu);

        // 5) output plane z: z-derivs from regs, xy-derivs from sf regs
        const float m0 = (fp_.t00 - t00m) + (yp.x - ym.x) + (xp.x - xm.x);
        const float m1 = (fp_.t01 - t01m) + (yp.y - ym.y) + (xp.y - xm.y);
        const float m2 = (fp_.t02 - t02m) + (yp.z - ym.z) + (xp.z - xm.z);
        const float en = (fp_.F0  - F0m)  + (yp.w - ym.w) + (xp.w - xm.w);

        __builtin_nontemporal_store(m0 * SCALE2, &out[1 * N3 + idx]);
        __builtin_nontemporal_store(m1 * SCALE2, &out[2 * N3 + idx]);
        __builtin_nontemporal_store(m2 * SCALE2, &out[3 * N3 + idx]);
        __builtin_nontemporal_store(en * SCALE2, &out[4 * N3 + idx]);

        // 6) deferred LDS writes: sf <- flux(z+1); dead u-slot <- u(z+3)
        sf_store(sfY, sfX, fi, fp_);
        if (hasH) sf_store(sfY, sfX, hfi, h);
        if (pref) { pW[q0] = r0; if (has2) pW[q1] = r1; }

        __syncthreads();

        // 7) rotate pipeline state (registers + slot pointers)
        t00m = t00c; t01m = t01c; t02m = t02c; F0m = F0c;
        t00c = fp_.t00; t01c = fp_.t01; t02c = fp_.t02; F0c = fp_.F0;
        rzm = rcc; rcc = own;
        if (hasH) { hzm = hcc; hcc = hown; }
        float4* t = pC; pC = pP; pP = pW; pW = t;
        idx += N2;
        if (++zw >= N) zw = 0;
    }
#undef STAGE_DIRECT
}

extern "C" void kernel_launch(void* const* d_in, const int* in_sizes, int n_in,
                              void* d_out, int out_size, void* d_ws, size_t ws_size,
                              hipStream_t stream)
{
    const float* u   = (const float*)d_in[0];   // [3, N, N, N]
    const float* T   = (const float*)d_in[1];   // [N, N, N]
    float*       out = (float*)d_out;           // [5, N, N, N]

    // mass channel is identically zero — write it with a memset, not 7M stores
    hipMemsetAsync(out, 0, (size_t)N3 * sizeof(float), stream);

    hipLaunchKernelGGL(diffusion_zmarch_kernel, dim3(NBLK), dim3(NT), 0, stream,
                       u, T, out);
}